// Round 1
// baseline (228.010 us; speedup 1.0000x reference)
//
#include <hip/hip_runtime.h>
#include <stdint.h>

// LIF scan: v += -v/TAU + I_t ; s = sigmoid(K*(v-TH)) ; hard = v>TH ; v *= (1-s)
// Outputs (concatenated float32): spikes[B*L], hard_latency[B], soft_latency[B]

constexpr float TAU_ = 20.0f;
constexpr float TH_  = 1.0f;
constexpr float K_   = 10.0f;
constexpr int   LDIM   = 4096;  // timesteps
constexpr int   TILE_T = 64;    // timesteps per LDS tile
constexpr int   NTILE  = LDIM / TILE_T;

// One LIF step. Returns surrogate spike s. Updates v (and latf when LAT).
template <bool LAT>
__device__ __forceinline__ float lif_step(float& v, float Iv, float tf, float& latf) {
  v = v + fmaf(v, -(1.0f / TAU_), Iv);            // Euler update
  float e = __expf(fmaf(-K_, v, K_));             // exp(-K*(v-TH))
  float s = __builtin_amdgcn_rcpf(1.0f + e);      // sigmoid (1 ulp rcp)
  if (LAT) {
    if (v > TH_) latf = fminf(latf, tf);          // first hard crossing (pre-reset v)
  }
  v = fmaf(-s, v, v);                             // v *= (1 - s)
  return s;
}

// ---- tile staging helpers (64 rows x 64 cols, float4-chunk XOR swizzle) ----
// LDS layout: float4 buf[64*16]; row r, chunk-position p -> buf[r*16 + p].
// Position p holds logical chunk g = p ^ (r & 15)  (involution).

__device__ __forceinline__ void load_tile(float4* stg, const float* __restrict__ I,
                                          int row0, int t0, int lane) {
  const int c     = lane & 15;   // chunk
  const int rbase = lane >> 4;   // sub-row 0..3
#pragma unroll
  for (int i = 0; i < 16; ++i) {
    const int r = 4 * i + rbase;
    stg[i] = *reinterpret_cast<const float4*>(
        I + (size_t)(row0 + r) * LDIM + t0 + 4 * c);   // coalesced 256B per 16 lanes
  }
}

__device__ __forceinline__ void write_tile(float4* bI, const float4* stg, int lane) {
  const int c     = lane & 15;
  const int rbase = lane >> 4;
#pragma unroll
  for (int i = 0; i < 16; ++i) {
    const int r = 4 * i + rbase;
    bI[r * 16 + (c ^ (r & 15))] = stg[i];              // swizzled ds_write_b128
  }
}

__device__ __forceinline__ void drain_tile(const float4* bS, float* __restrict__ gOut,
                                           int lane) {
  const int c     = lane & 15;
  const int rbase = lane >> 4;
#pragma unroll
  for (int i = 0; i < 16; ++i) {
    const int r = 4 * i + rbase;
    float4 vdat = bS[r * 16 + (c ^ (r & 15))];         // swizzled ds_read_b128
    *reinterpret_cast<float4*>(gOut + (size_t)r * LDIM + 4 * c) = vdat;  // linear store
  }
}

// Process one 64-step tile: per-lane row = lane. Reads swizzled I chunks,
// writes swizzled S chunks. Accumulates ss (sum s), sst (sum s*t).
template <bool LAT>
__device__ __forceinline__ void process_tile(const float4* __restrict__ bI,
                                             float4* __restrict__ bS, int lane,
                                             float& v, float& latf,
                                             float& ss, float& sst, float& tf) {
  const int m    = lane & 15;
  const int base = lane * 16;
  float4 c = bI[base + (0 ^ m)];                  // prefetch group 0
#pragma unroll
  for (int j = 0; j < 16; ++j) {
    float4 Ij = c;
    if (j + 1 < 16) c = bI[base + ((j + 1) ^ m)]; // prefetch next group
    float4 S;
    S.x = lif_step<LAT>(v, Ij.x, tf + 0.0f, latf);
    S.y = lif_step<LAT>(v, Ij.y, tf + 1.0f, latf);
    S.z = lif_step<LAT>(v, Ij.z, tf + 2.0f, latf);
    S.w = lif_step<LAT>(v, Ij.w, tf + 3.0f, latf);
    // sum s and sum s*t, decomposed: sum s_j*(tf+j) = tf*g + (S.y + 2 S.z + 3 S.w)
    float g = (S.x + S.y) + (S.z + S.w);
    ss += g;
    sst = fmaf(g, tf, sst);
    sst += S.y;
    sst = fmaf(2.0f, S.z, sst);
    sst = fmaf(3.0f, S.w, sst);
    tf += 4.0f;
    bS[base + (j ^ m)] = S;
  }
}

extern "C" __global__ void __launch_bounds__(64) lif_kernel(
    const float* __restrict__ I, float* __restrict__ spikes,
    float* __restrict__ hardLat, float* __restrict__ softLat) {
  __shared__ float4 bufI[2][64 * 16];   // double-buffered I tiles (32 KiB)
  __shared__ float4 bufS[64 * 16];      // spikes tile (16 KiB)

  const int lane = threadIdx.x;         // 0..63, owns row row0+lane
  const int row0 = blockIdx.x * 64;
  const int row  = row0 + lane;

  float v = 0.0f;
  float latf = (float)LDIM;             // 4096 = "never fired"
  float ss = 0.0f, sst = 0.0f, tf = 0.0f;
  float4 stg[16];

  // prologue: stage tile 0
  load_tile(stg, I, row0, 0, lane);
  write_tile(bufI[0], stg, lane);

  int cur = 0;
  for (int k = 0; k < NTILE; ++k) {
    if (k + 1 < NTILE)
      load_tile(stg, I, row0, (k + 1) * TILE_T, lane);   // issue early, lands under compute

    // phase split: drop latency tracking once every lane has fired
    const bool need_lat = !__all(latf < (float)LDIM);
    if (need_lat)
      process_tile<true >(bufI[cur], bufS, lane, v, latf, ss, sst, tf);
    else
      process_tile<false>(bufI[cur], bufS, lane, v, latf, ss, sst, tf);

    drain_tile(bufS, spikes + (size_t)row0 * LDIM + k * TILE_T, lane);

    if (k + 1 < NTILE)
      write_tile(bufI[cur ^ 1], stg, lane);              // vmcnt wait folded here
    cur ^= 1;
  }

  hardLat[row] = latf;                  // first crossing index, else 4096
  softLat[row] = sst / (ss + 1e-6f);    // weighted mean spike time
}

extern "C" void kernel_launch(void* const* d_in, const int* in_sizes, int n_in,
                              void* d_out, int out_size, void* d_ws, size_t ws_size,
                              hipStream_t stream) {
  const float* I = (const float*)d_in[0];
  const int B = in_sizes[0] / LDIM;     // 8192
  float* out    = (float*)d_out;
  float* spikes = out;                          // [B*L]
  float* hard   = out + (size_t)B * LDIM;       // [B]
  float* soft   = hard + B;                     // [B]

  dim3 grid(B / 64), block(64);
  hipLaunchKernelGGL(lif_kernel, grid, block, 0, stream, I, spikes, hard, soft);
}

// Round 2
// 127.200 us; speedup vs baseline: 1.7925x; 1.7925x over previous
//
#include <hip/hip_runtime.h>
#include <stdint.h>

// LIF scan, chunk-parallel with warm-up convergence.
// v' = fma(v, 0.95, I); s = sigmoid(10(v'-1)); hard = v'>1; v'' = v'*(1-s)
// Outputs (f32, concat): spikes[B*L], hard_latency[B], soft_latency[B]

constexpr float TH_   = 1.0f;
constexpr float LEAK  = 0.95f;                   // 1 - 1/tau
constexpr float KL2E  = 14.426950408889634f;     // K * log2(e)
constexpr int   LDIM   = 4096;
constexpr int   TILE_T = 32;                     // timesteps per LDS tile
constexpr int   CH     = TILE_T / 4;             // 8 float4 chunks per row-tile
constexpr int   NCHUNK = 16;                     // time-parallel chunks
constexpr int   WARM   = 256;                    // warm-up steps (state convergence)

__device__ __forceinline__ float exp2_fast(float x) {
#if __has_builtin(__builtin_amdgcn_exp2f)
  return __builtin_amdgcn_exp2f(x);
#else
  return exp2f(x);
#endif
}

// One LIF step. Returns surrogate s; updates v (and latf when LAT).
template <bool LAT>
__device__ __forceinline__ float lif_step(float& v, float Iv, float tf, float& latf) {
  v = fmaf(v, LEAK, Iv);                       // Euler, fused
  float e = exp2_fast(fmaf(-KL2E, v, KL2E));   // exp(-K*(v-TH)) in exp2 domain
  float s = __builtin_amdgcn_rcpf(1.0f + e);   // sigmoid
  if (LAT) {
    if (v > TH_) latf = fminf(latf, tf);       // first hard crossing (pre-reset v)
  }
  v = fmaf(-s, v, v);                          // v *= (1 - s)
  return s;
}

// ---- 64 rows x TILE_T cols staging, float4-chunk XOR swizzle ----
// LDS: float4 buf[64*CH]; row r, position p holds logical chunk p ^ (r&(CH-1)).

__device__ __forceinline__ void load_tile(float4* stg, const float* __restrict__ I,
                                          int row0, int t0, int lane) {
  const int c     = lane & (CH - 1);
  const int rbase = lane / CH;                 // 0..7
#pragma unroll
  for (int i = 0; i < CH; ++i) {
    const int r = 8 * i + rbase;
    stg[i] = *reinterpret_cast<const float4*>(
        I + (size_t)(row0 + r) * LDIM + t0 + 4 * c);   // 8 lanes = 128B coalesced
  }
}

__device__ __forceinline__ void write_tile(float4* bI, const float4* stg, int lane) {
  const int c     = lane & (CH - 1);
  const int rbase = lane / CH;
#pragma unroll
  for (int i = 0; i < CH; ++i) {
    const int r = 8 * i + rbase;
    bI[r * CH + (c ^ (r & (CH - 1)))] = stg[i];
  }
}

__device__ __forceinline__ void drain_tile(const float4* bS, float* __restrict__ gOut,
                                           int lane) {
  const int c     = lane & (CH - 1);
  const int rbase = lane / CH;
#pragma unroll
  for (int i = 0; i < CH; ++i) {
    const int r = 8 * i + rbase;
    float4 vd = bS[r * CH + (c ^ (r & (CH - 1)))];
    *reinterpret_cast<float4*>(gOut + (size_t)r * LDIM + 4 * c) = vd;
  }
}

template <bool LAT>
__device__ __forceinline__ void process_tile(const float4* __restrict__ bI,
                                             float4* __restrict__ bS, int lane,
                                             float& v, float& latf,
                                             float& ss, float& sst, float& tf) {
  const int m    = lane & (CH - 1);
  const int base = lane * CH;
  float4 c = bI[base + (0 ^ m)];
#pragma unroll
  for (int j = 0; j < CH; ++j) {
    float4 Ij = c;
    if (j + 1 < CH) c = bI[base + ((j + 1) ^ m)];
    float4 S;
    S.x = lif_step<LAT>(v, Ij.x, tf + 0.0f, latf);
    S.y = lif_step<LAT>(v, Ij.y, tf + 1.0f, latf);
    S.z = lif_step<LAT>(v, Ij.z, tf + 2.0f, latf);
    S.w = lif_step<LAT>(v, Ij.w, tf + 3.0f, latf);
    float g = (S.x + S.y) + (S.z + S.w);       // Σ s over the 4 steps
    ss += g;
    sst = fmaf(g, tf, sst);                    // Σ s·t decomposition
    sst += S.y;
    sst = fmaf(2.0f, S.z, sst);
    sst = fmaf(3.0f, S.w, sst);
    tf += 4.0f;
    bS[base + (j ^ m)] = S;
  }
}

__device__ __forceinline__ void process_warm(const float4* __restrict__ bI, int lane,
                                             float& v) {
  const int m    = lane & (CH - 1);
  const int base = lane * CH;
  float dummy = 0.0f;
  float4 c = bI[base + (0 ^ m)];
#pragma unroll
  for (int j = 0; j < CH; ++j) {
    float4 Ij = c;
    if (j + 1 < CH) c = bI[base + ((j + 1) ^ m)];
    lif_step<false>(v, Ij.x, 0.0f, dummy);
    lif_step<false>(v, Ij.y, 0.0f, dummy);
    lif_step<false>(v, Ij.z, 0.0f, dummy);
    lif_step<false>(v, Ij.w, 0.0f, dummy);
  }
}

// DIRECT=false: per-(chunk,row) partials into pA(Σs)/pB(Σs·t)/pL(first-t).
// DIRECT=true : single-chunk fallback; pA<-soft, pL<-hard directly.
template <bool DIRECT>
__global__ void __launch_bounds__(64) lif_scan(
    const float* __restrict__ I, float* __restrict__ spikes,
    float* __restrict__ pA, float* __restrict__ pB, float* __restrict__ pL,
    int B, int own, int warm) {
  __shared__ float4 bufI[64 * CH];   // 8 KiB
  __shared__ float4 bufS[64 * CH];   // 8 KiB

  const int lane  = threadIdx.x;
  const int row0  = blockIdx.x * 64;
  const int row   = row0 + lane;
  const int chunk = blockIdx.y;

  const int t_own  = chunk * own;
  const int t_beg  = (chunk == 0) ? 0 : t_own - warm;
  const int nwarm  = (t_own - t_beg) / TILE_T;
  const int ntile  = nwarm + own / TILE_T;

  float v = 0.0f;
  float latf = (float)LDIM;
  float ss = 0.0f, sst = 0.0f;
  float tf = (float)t_own;           // absolute step index for owned region
  float4 stg[CH];

  load_tile(stg, I, row0, t_beg, lane);
  write_tile(bufI, stg, lane);

  for (int k = 0; k < ntile; ++k) {
    if (k + 1 < ntile)
      load_tile(stg, I, row0, t_beg + (k + 1) * TILE_T, lane);  // in flight under compute

    if (k < nwarm) {
      process_warm(bufI, lane, v);
    } else {
      const bool need_lat = !__all(latf < (float)LDIM);
      if (need_lat) process_tile<true >(bufI, bufS, lane, v, latf, ss, sst, tf);
      else          process_tile<false>(bufI, bufS, lane, v, latf, ss, sst, tf);
      drain_tile(bufS, spikes + (size_t)row0 * LDIM + t_beg + k * TILE_T, lane);
    }

    if (k + 1 < ntile)
      write_tile(bufI, stg, lane);   // vmcnt wait lands here, after compute
  }

  if (DIRECT) {
    pL[row] = latf;
    pA[row] = sst / (ss + 1e-6f);
  } else {
    const size_t o = (size_t)chunk * B + row;
    pA[o] = ss;
    pB[o] = sst;
    pL[o] = latf;
  }
}

extern "C" __global__ void __launch_bounds__(256) lif_reduce(
    const float* __restrict__ pA, const float* __restrict__ pB,
    const float* __restrict__ pL, float* __restrict__ hard,
    float* __restrict__ soft, int B) {
  const int r = blockIdx.x * 256 + threadIdx.x;
  if (r >= B) return;
  float a = 0.0f, b = 0.0f, l = (float)LDIM;
  for (int c = 0; c < NCHUNK; ++c) {
    a += pA[(size_t)c * B + r];
    b += pB[(size_t)c * B + r];
    l = fminf(l, pL[(size_t)c * B + r]);
  }
  hard[r] = l;
  soft[r] = b / (a + 1e-6f);
}

extern "C" void kernel_launch(void* const* d_in, const int* in_sizes, int n_in,
                              void* d_out, int out_size, void* d_ws, size_t ws_size,
                              hipStream_t stream) {
  const float* I = (const float*)d_in[0];
  const int B = in_sizes[0] / LDIM;            // 8192
  float* out    = (float*)d_out;
  float* spikes = out;
  float* hard   = out + (size_t)B * LDIM;
  float* soft   = hard + B;

  const size_t need = (size_t)3 * NCHUNK * B * sizeof(float);
  if (ws_size >= need) {
    float* pA = (float*)d_ws;
    float* pB = pA + (size_t)NCHUNK * B;
    float* pL = pB + (size_t)NCHUNK * B;
    hipLaunchKernelGGL((lif_scan<false>), dim3(B / 64, NCHUNK), dim3(64), 0, stream,
                       I, spikes, pA, pB, pL, B, LDIM / NCHUNK, WARM);
    hipLaunchKernelGGL(lif_reduce, dim3((B + 255) / 256), dim3(256), 0, stream,
                       pA, pB, pL, hard, soft, B);
  } else {
    // fallback: single chunk, direct outputs (hard<-pL, soft<-pA)
    hipLaunchKernelGGL((lif_scan<true>), dim3(B / 64, 1), dim3(64), 0, stream,
                       I, spikes, soft, soft, hard, B, LDIM, 0);
  }
}